// Round 12
// baseline (195.810 us; speedup 1.0000x reference)
//
#include <hip/hip_runtime.h>

#define T_TOKENS 16384
#define DIM 2048
#define NE 8
#define QOUT 2048
#define LSCALE 2.0f

typedef __attribute__((ext_vector_type(4))) float f32x4;
typedef __attribute__((ext_vector_type(8))) short s16x8;
typedef __attribute__((ext_vector_type(4))) short s16x4;

__device__ __forceinline__ short f2bf(float f) {
  unsigned u = __builtin_bit_cast(unsigned, f);
  u += 0x7fffu + ((u >> 16) & 1u);   // round-to-nearest-even
  return (short)(u >> 16);
}

__device__ __forceinline__ s16x8 pack8(float4 a, float4 b) {
  s16x8 r;
  r[0] = f2bf(a.x); r[1] = f2bf(a.y); r[2] = f2bf(a.z); r[3] = f2bf(a.w);
  r[4] = f2bf(b.x); r[5] = f2bf(b.y); r[6] = f2bf(b.z); r[7] = f2bf(b.w);
  return r;
}

__device__ __forceinline__ void barrier_lds() {
  asm volatile("s_waitcnt lgkmcnt(0)" ::: "memory");
  __builtin_amdgcn_s_barrier();
}

// ---------------------------------------------------------------------------
// Pack LoRA weights (f32) into bf16 MFMA-fragment layout.
// lora_a [E][D][R]  -> P1[d8][col=e*16+r][j]  (d = d8*8+j), col in [0,128)
// lora_b [E][R][QO] -> P2[k8][c][j]           (k = k8*8+j = e*16+r)
// ---------------------------------------------------------------------------
__global__ __launch_bounds__(256) void k_pack(
    const float* __restrict__ qa, const float* __restrict__ qb,
    const float* __restrict__ va, const float* __restrict__ vb,
    short* __restrict__ Bq1, short* __restrict__ Bv1,
    short* __restrict__ Bq2, short* __restrict__ Bv2) {
  int tid = blockIdx.x * 256 + threadIdx.x;  // 131072 threads
  if (tid < 65536) {
    int mat = tid >> 15;
    int idx = tid & 32767;          // d8*128 + col
    int d8 = idx >> 7, c = idx & 127;
    int e = c >> 4, r = c & 15;
    const float* src = mat ? va : qa;
    short* dst = mat ? Bv1 : Bq1;
    s16x8 v;
#pragma unroll
    for (int j = 0; j < 8; ++j)
      v[j] = f2bf(src[((size_t)e * DIM + d8 * 8 + j) * 16 + r]);
    *(s16x8*)(dst + (size_t)idx * 8) = v;
  } else {
    int t2 = tid - 65536;
    int mat = t2 >> 15;
    int idx = t2 & 32767;           // k8*2048 + c
    int k8 = idx >> 11, c = idx & 2047;
    const float* src = mat ? vb : qb;
    short* dst = mat ? Bv2 : Bq2;
    s16x8 v;
#pragma unroll
    for (int j = 0; j < 8; ++j)
      v[j] = f2bf(src[(size_t)(k8 * 8 + j) * QOUT + c]);
    *(s16x8*)(dst + (size_t)idx * 8) = v;
  }
}

// ---------------------------------------------------------------------------
// Fused, BARRIER-FREE phase A (R11 post-mortem: 32 barriers/block at 2
// blocks/CU lockstep-drained the CU; all pipes <30%).
//
// Block = 32 tokens, 512 threads (8 waves), grid 512.  LDS 17.5 KB.
// Phase A: NO LDS staging, NO barriers.  Each lane loads its MFMA A-frag
// directly from h (lane=token lrow, k-slice lk*8; h is L3-resident across
// replays — FETCH_SIZE 78MB < 128MB proved it).  Wave wv: token half
// th=wv>>2, 64 concat cols colq=(wv&3)*64, acc1[4].  Routing: 2 experts
// per wave (e0=colq*2), raw logits -> LDS once; softmax/top-2 recomputed
// per-thread after ONE barrier (f32-exact, deterministic).
// Phase B: as R10's best (a2 preload, unroll 4, depth-1 B2 prefetch,
// nontemporal stores).  Total barriers per block: 2.
// ---------------------------------------------------------------------------
__global__ __launch_bounds__(512) void k_fused(
    const float* __restrict__ h, const float* __restrict__ rw,
    const short* __restrict__ Bq1, const short* __restrict__ Bv1,
    const short* __restrict__ Bq2, const short* __restrict__ Bv2,
    float* __restrict__ out) {
  __shared__ float wraw[32][NE];    // raw router logits (1 KB)
  __shared__ short low[32][264];    // 32 tok x 256 cols bf16, padded (16.5 KB)

  const int tid = threadIdx.x;
  const int lane = tid & 63, wv = tid >> 6;
  const int lrow = lane & 15, lk = lane >> 4;
  const int row0 = blockIdx.x * 32;
  const int th = wv >> 2;               // token half (0/1)
  const int colq = wv & 3;              // 64-col quarter of concat space
  const int tok = th * 16 + lrow;       // this lane's token (block-local)

  const float* hl = h + (size_t)(row0 + tok) * DIM + lk * 8;
  const short* B1 = (colq >= 2) ? Bv1 : Bq1;
  const int e0 = colq * 2;              // routing experts e0, e0+1
  const float* rwl0 = rw + (size_t)e0 * DIM + lk * 8;
  const float* rwl1 = rwl0 + DIM;
  int cc[4];
#pragma unroll
  for (int ct = 0; ct < 4; ++ct) cc[ct] = (colq & 1) * 64 + ct * 16 + lrow;

  float lg0 = 0.f, lg1 = 0.f;
  f32x4 acc1[4] = {};

#pragma unroll 2
  for (int kb = 0; kb < DIM; kb += 32) {
    float4 h0 = *(const float4*)(hl + kb);
    float4 h1 = *(const float4*)(hl + kb + 4);
    s16x8 b[4];
    const int d8 = (kb >> 3) + lk;
#pragma unroll
    for (int ct = 0; ct < 4; ++ct)
      b[ct] = *(const s16x8*)(B1 + ((size_t)d8 * 128 + cc[ct]) * 8);
    float4 r0 = *(const float4*)(rwl0 + kb);
    float4 r1 = *(const float4*)(rwl0 + kb + 4);
    float4 r2 = *(const float4*)(rwl1 + kb);
    float4 r3 = *(const float4*)(rwl1 + kb + 4);
    lg0 += h0.x * r0.x + h0.y * r0.y + h0.z * r0.z + h0.w * r0.w
         + h1.x * r1.x + h1.y * r1.y + h1.z * r1.z + h1.w * r1.w;
    lg1 += h0.x * r2.x + h0.y * r2.y + h0.z * r2.z + h0.w * r2.w
         + h1.x * r3.x + h1.y * r3.y + h1.z * r3.z + h1.w * r3.w;
    s16x8 a = pack8(h0, h1);
#pragma unroll
    for (int ct = 0; ct < 4; ++ct)
      acc1[ct] = __builtin_amdgcn_mfma_f32_16x16x32_bf16(b[ct], a, acc1[ct], 0, 0, 0);
  }

  // logits: reduce over the 4 lk-groups (lanes tok, tok+16, tok+32, tok+48)
  lg0 += __shfl_xor(lg0, 16, 64); lg0 += __shfl_xor(lg0, 32, 64);
  lg1 += __shfl_xor(lg1, 16, 64); lg1 += __shfl_xor(lg1, 32, 64);
  if (lk == 0) wraw[tok][e0] = lg0;        // lanes 0-15
  if (lk == 1) wraw[tok][e0 + 1] = lg1;    // lanes 16-31 (hold token lrow's sum)

  // phase-B prologue loads: independent of low; hide under barrier+softmax
  const int m = wv >> 2;                   // 0=q, 1=v
  const int cwave = (wv & 3) * 512;        // col group within m
  const short* B2 = m ? Bv2 : Bq2;
  s16x8 bc[4];
#pragma unroll
  for (int ct = 0; ct < 4; ++ct) {
    int c = cwave + ct * 16 + lrow;        // sub=0, kk=0 -> k8 = lk
    bc[ct] = *(const s16x8*)(B2 + ((size_t)lk * QOUT + c) * 8);
  }

  barrier_lds();                           // wraw visible

  // per-thread softmax + top-2 over this lane's token (deterministic)
  float p[NE], sum = 0.f;
  {
    float l[NE];
#pragma unroll
    for (int e = 0; e < NE; ++e) l[e] = wraw[tok][e];
    float mx = l[0];
#pragma unroll
    for (int e = 1; e < NE; ++e) mx = fmaxf(mx, l[e]);
#pragma unroll
    for (int e = 0; e < NE; ++e) { p[e] = expf(l[e] - mx); sum += p[e]; }
  }
  int i1 = 0; float v1 = p[0];
#pragma unroll
  for (int e = 1; e < NE; ++e) if (p[e] > v1) { v1 = p[e]; i1 = e; }
  float v2 = -1.f; int i2 = 0;
#pragma unroll
  for (int e = 0; e < NE; ++e) if (e != i1 && p[e] > v2) { v2 = p[e]; i2 = e; }
  float s1 = v1 / sum, s2 = v2 / sum;
  float dn = s1 + s2 + 1e-20f;
  float w1 = s1 / dn * LSCALE, w2 = s2 / dn * LSCALE;

  // scale + write low (token=lrow axis of C; cols=lk*4+j):
  // concat col c = colq*64+ct*16+lk*4+j -> e = (colq&1)*4 + ct
#pragma unroll
  for (int ct = 0; ct < 4; ++ct) {
    int e = (colq & 1) * 4 + ct;
    float wgt = (e == i1) ? w1 : ((e == i2) ? w2 : 0.f);
    s16x4 v;
#pragma unroll
    for (int j = 0; j < 4; ++j) v[j] = f2bf(acc1[ct][j] * wgt);
    *(s16x4*)&low[tok][colq * 64 + ct * 16 + lk * 4] = v;
  }
  barrier_lds();                           // low visible

  // -------------------- phase B: out = low @ B2 --------------------
  float* op = out + (size_t)m * T_TOKENS * QOUT;
  s16x8 a2[2][4];
#pragma unroll
  for (int rt = 0; rt < 2; ++rt)
#pragma unroll
    for (int kk = 0; kk < 4; ++kk)
      a2[rt][kk] = *(const s16x8*)&low[rt * 16 + lrow][m * 128 + kk * 32 + lk * 8];

  f32x4 acc[2][4] = {};
#pragma unroll 4
  for (int it = 0; it < 32; ++it) {
    const int sub = it >> 2, kk = it & 3;  // kk static under unroll 4
    const int itn = (it + 1) & 31;         // wraps (dead) on last iter
    const int subn = itn >> 2, kkn = itn & 3;
    s16x8 bn[4];
#pragma unroll
    for (int ct = 0; ct < 4; ++ct) {
      int c = cwave + subn * 64 + ct * 16 + lrow;
      bn[ct] = *(const s16x8*)(B2 + ((size_t)(kkn * 4 + lk) * QOUT + c) * 8);
    }
#pragma unroll
    for (int rt = 0; rt < 2; ++rt)
#pragma unroll
      for (int ct = 0; ct < 4; ++ct)
        acc[rt][ct] = __builtin_amdgcn_mfma_f32_16x16x32_bf16(bc[ct], a2[rt][kk], acc[rt][ct], 0, 0, 0);
    if (kk == 3) {
      int cb = cwave + sub * 64;
#pragma unroll
      for (int rt = 0; rt < 2; ++rt)
#pragma unroll
        for (int ct = 0; ct < 4; ++ct) {
          int t = row0 + rt * 16 + lrow;
          int col = cb + ct * 16 + lk * 4;
          __builtin_nontemporal_store(acc[rt][ct], (f32x4*)(op + (size_t)t * QOUT + col));
          acc[rt][ct] = (f32x4){0.f, 0.f, 0.f, 0.f};
        }
    }
#pragma unroll
    for (int ct = 0; ct < 4; ++ct) bc[ct] = bn[ct];
  }
}

extern "C" void kernel_launch(void* const* d_in, const int* in_sizes, int n_in,
                              void* d_out, int out_size, void* d_ws, size_t ws_size,
                              hipStream_t stream) {
  const float* h  = (const float*)d_in[0];
  const float* rw = (const float*)d_in[1];
  const float* qa = (const float*)d_in[2];
  const float* qb = (const float*)d_in[3];
  const float* va = (const float*)d_in[4];
  const float* vb = (const float*)d_in[5];
  float* out = (float*)d_out;
  char* ws = (char*)d_ws;

  short* Bq1 = (short*)(ws);                    // 512 KB each
  short* Bv1 = (short*)(ws + (512 << 10));
  short* Bq2 = (short*)(ws + (1024 << 10));
  short* Bv2 = (short*)(ws + (1536 << 10));

  k_pack<<<512, 256, 0, stream>>>(qa, qb, va, vb, Bq1, Bv1, Bq2, Bv2);
  k_fused<<<T_TOKENS / 32, 512, 0, stream>>>(h, rw, Bq1, Bv1, Bq2, Bv2, out);
}

// Round 13
// 180.388 us; speedup vs baseline: 1.0855x; 1.0855x over previous
//
#include <hip/hip_runtime.h>

#define T_TOKENS 16384
#define DIM 2048
#define NE 8
#define QOUT 2048
#define LSCALE 2.0f

typedef __attribute__((ext_vector_type(4))) float f32x4;
typedef __attribute__((ext_vector_type(8))) short s16x8;
typedef __attribute__((ext_vector_type(4))) short s16x4;

__device__ __forceinline__ short f2bf(float f) {
  unsigned u = __builtin_bit_cast(unsigned, f);
  u += 0x7fffu + ((u >> 16) & 1u);   // round-to-nearest-even
  return (short)(u >> 16);
}

__device__ __forceinline__ void barrier_lds() {
  asm volatile("s_waitcnt lgkmcnt(0)" ::: "memory");
  __builtin_amdgcn_s_barrier();
}

// ---------------------------------------------------------------------------
// Pack LoRA weights (f32) into bf16 MFMA-fragment layout.
// lora_a [E][D][R]  -> P1[d8][col=e*16+r][j]  (d = d8*8+j), col in [0,128)
// lora_b [E][R][QO] -> P2[k8][c][j]           (k = k8*8+j = e*16+r)
// ---------------------------------------------------------------------------
__global__ __launch_bounds__(256) void k_pack(
    const float* __restrict__ qa, const float* __restrict__ qb,
    const float* __restrict__ va, const float* __restrict__ vb,
    short* __restrict__ Bq1, short* __restrict__ Bv1,
    short* __restrict__ Bq2, short* __restrict__ Bv2) {
  int tid = blockIdx.x * 256 + threadIdx.x;  // 131072 threads
  if (tid < 65536) {
    int mat = tid >> 15;
    int idx = tid & 32767;          // d8*128 + col
    int d8 = idx >> 7, c = idx & 127;
    int e = c >> 4, r = c & 15;
    const float* src = mat ? va : qa;
    short* dst = mat ? Bv1 : Bq1;
    s16x8 v;
#pragma unroll
    for (int j = 0; j < 8; ++j)
      v[j] = f2bf(src[((size_t)e * DIM + d8 * 8 + j) * 16 + r]);
    *(s16x8*)(dst + (size_t)idx * 8) = v;
  } else {
    int t2 = tid - 65536;
    int mat = t2 >> 15;
    int idx = t2 & 32767;           // k8*2048 + c
    int k8 = idx >> 11, c = idx & 2047;
    const float* src = mat ? vb : qb;
    short* dst = mat ? Bv2 : Bq2;
    s16x8 v;
#pragma unroll
    for (int j = 0; j < 8; ++j)
      v[j] = f2bf(src[(size_t)(k8 * 8 + j) * QOUT + c]);
    *(s16x8*)(dst + (size_t)idx * 8) = v;
  }
}

// ---------------------------------------------------------------------------
// Fused: routing + stage1 (low in LDS) + stage2 (f32 out).
// R13: 16-token blocks, 256 threads (4 waves), grid 1024 -> 4 blocks/CU
// (R8-R12 were grid-limited to 2 blocks/CU -> occupancy stuck at 40%).
// LDS 13.3 KB.  Per-phase live regs ~80 (acc arrays halved vs 32-tok).
//
// Phase A (K=2048, BK=64): thread (r=tid>>4, kq=(tid&15)*4) stages one
// float4 of the 16x64 h tile into At (dbuf, bf16); all-8-expert routing
// partials vs global rw (f32-exact); wave wv owns 64 concat cols.
// Epilogue: 16-lane shfl reduce -> per-thread softmax/top-2 -> wl.
// Phase B (K=128): wave wv owns m=wv>>1 (q/v), cols (wv&1)*1024..+1023;
// a2[4] preload from low-LDS; 64 flattened (sub,kk) iters, depth-1 B2
// prefetch, nontemporal f32x4 stores.
// ---------------------------------------------------------------------------
__global__ __launch_bounds__(256) void k_fused(
    const float* __restrict__ h, const float* __restrict__ rw,
    const short* __restrict__ Bq1, const short* __restrict__ Bv1,
    const short* __restrict__ Bq2, const short* __restrict__ Bv2,
    float* __restrict__ out) {
  __shared__ short At[2][16][72];   // 16 tok x 64 k bf16, 144B rows (4.5 KB)
  __shared__ short low[16][264];    // 16 tok x 256 cols bf16 (8.25 KB)
  __shared__ float wl[16][NE];      // 0.5 KB

  const int tid = threadIdx.x;
  const int lane = tid & 63, wv = tid >> 6;
  const int lrow = lane & 15, lk = lane >> 4;
  const int row0 = blockIdx.x * 16;
  const int r  = tid >> 4;              // 0..15: token row this thread stages
  const int kq = (tid & 15) * 4;        // k-offset within 64-wide step

  const float* hrow = h + (size_t)(row0 + r) * DIM + kq;
  // phase-A: wave wv owns concat cols [wv*64, wv*64+64)
  const short* B1 = (wv >= 2) ? Bv1 : Bq1;
  int cc[4];
#pragma unroll
  for (int ct = 0; ct < 4; ++ct) cc[ct] = (wv & 1) * 64 + ct * 16 + lrow;

  float4 hv = *(const float4*)(hrow);   // depth-1 prefetch

  float lg[NE] = {0.f, 0.f, 0.f, 0.f, 0.f, 0.f, 0.f, 0.f};
  f32x4 acc1[4] = {};

#pragma unroll 1
  for (int kb = 0; kb < DIM; kb += 64) {
    const int cur = (kb >> 6) & 1;      // uniform -> SALU addressing
    float4 hvn = *(const float4*)(hrow + ((kb + 64) & (DIM - 1)));  // dead on tail
    // this-step B1 fragments (distinct per wave)
    s16x8 bA[4], bB[4];
#pragma unroll
    for (int ct = 0; ct < 4; ++ct) {
      int d8 = (kb >> 3) + lk;
      bA[ct] = *(const s16x8*)(B1 + ((size_t)d8 * 128 + cc[ct]) * 8);
      bB[ct] = *(const s16x8*)(B1 + ((size_t)(d8 + 4) * 128 + cc[ct]) * 8);
    }
    // stage A tile (bf16)
    s16x4 hb4;
    hb4[0] = f2bf(hv.x); hb4[1] = f2bf(hv.y);
    hb4[2] = f2bf(hv.z); hb4[3] = f2bf(hv.w);
    *(s16x4*)&At[cur][r][kq] = hb4;
    // routing partials vs global rw (f32-exact), 2 groups of 4
#pragma unroll 1
    for (int g = 0; g < 2; ++g) {
#pragma unroll
      for (int e = 0; e < 4; ++e) {
        float4 rv = *(const float4*)(rw + (g * 4 + e) * DIM + kb + kq);
        lg[g * 4 + e] += hv.x * rv.x + hv.y * rv.y + hv.z * rv.z + hv.w * rv.w;
      }
    }
    barrier_lds();                       // lgkm drain only; vmcnt stays
    s16x8 a0 = *(const s16x8*)&At[cur][lrow][lk * 8];
    s16x8 a1 = *(const s16x8*)&At[cur][lrow][32 + lk * 8];
#pragma unroll
    for (int ct = 0; ct < 4; ++ct) {
      acc1[ct] = __builtin_amdgcn_mfma_f32_16x16x32_bf16(bA[ct], a0, acc1[ct], 0, 0, 0);
      acc1[ct] = __builtin_amdgcn_mfma_f32_16x16x32_bf16(bB[ct], a1, acc1[ct], 0, 0, 0);
    }
    hv = hvn;
  }

  // reduce logits across the 16 k-lanes of each token row (16-aligned groups)
#pragma unroll
  for (int e = 0; e < NE; ++e) {
    lg[e] += __shfl_xor(lg[e], 1, 64);
    lg[e] += __shfl_xor(lg[e], 2, 64);
    lg[e] += __shfl_xor(lg[e], 4, 64);
    lg[e] += __shfl_xor(lg[e], 8, 64);
  }
  // softmax + top-2 (redundant across the 16 lanes of a row; deterministic)
  float mx = lg[0];
#pragma unroll
  for (int e = 1; e < NE; ++e) mx = fmaxf(mx, lg[e]);
  float p[NE], sum = 0.f;
#pragma unroll
  for (int e = 0; e < NE; ++e) { p[e] = expf(lg[e] - mx); sum += p[e]; }
  int i1 = 0; float v1 = p[0];
#pragma unroll
  for (int e = 1; e < NE; ++e) if (p[e] > v1) { v1 = p[e]; i1 = e; }
  float v2 = -1.f; int i2 = 0;
#pragma unroll
  for (int e = 0; e < NE; ++e) if (e != i1 && p[e] > v2) { v2 = p[e]; i2 = e; }
  float s1 = v1 / sum, s2 = v2 / sum;
  float dn = s1 + s2 + 1e-20f;
  float w1 = s1 / dn * LSCALE, w2 = s2 / dn * LSCALE;
  if ((tid & 15) < 8) {
    int el = tid & 7;
    wl[r][el] = (el == i1) ? w1 : ((el == i2) ? w2 : 0.f);
  }

  // phase-B prologue loads (independent of low; hide under barrier+epilogue)
  const int m = wv >> 1;                  // 0=q, 1=v
  const int cwave = (wv & 1) * 1024;      // col half within m
  const short* B2 = m ? Bv2 : Bq2;
  s16x8 bc[4];
#pragma unroll
  for (int ct = 0; ct < 4; ++ct) {
    int c = cwave + ct * 16 + lrow;       // sub=0, kk=0 -> k8 = lk
    bc[ct] = *(const s16x8*)(B2 + ((size_t)lk * QOUT + c) * 8);
  }

  barrier_lds();                          // wl visible (+ last At reads done)

  // scale + write low (token=lrow, cols=lk*4+j).  e = (wv&1)*4 + ct
#pragma unroll
  for (int ct = 0; ct < 4; ++ct) {
    float wgt = wl[lrow][(wv & 1) * 4 + ct];
    s16x4 v;
#pragma unroll
    for (int j = 0; j < 4; ++j) v[j] = f2bf(acc1[ct][j] * wgt);
    *(s16x4*)&low[lrow][wv * 64 + ct * 16 + lk * 4] = v;
  }
  barrier_lds();                          // low visible

  // -------------------- phase B: out = low @ B2 --------------------
  float* op = out + (size_t)m * T_TOKENS * QOUT;
  s16x8 a2[4];
#pragma unroll
  for (int kk = 0; kk < 4; ++kk)
    a2[kk] = *(const s16x8*)&low[lrow][m * 128 + kk * 32 + lk * 8];

  f32x4 acc[4] = {};
#pragma unroll 4
  for (int it = 0; it < 64; ++it) {
    const int sub = it >> 2, kk = it & 3;  // kk static under unroll 4
    const int itn = (it + 1) & 63;         // wraps (dead) on last iter
    const int subn = itn >> 2, kkn = itn & 3;
    s16x8 bn[4];
#pragma unroll
    for (int ct = 0; ct < 4; ++ct) {
      int c = cwave + subn * 64 + ct * 16 + lrow;
      bn[ct] = *(const s16x8*)(B2 + ((size_t)(kkn * 4 + lk) * QOUT + c) * 8);
    }
#pragma unroll
    for (int ct = 0; ct < 4; ++ct)
      acc[ct] = __builtin_amdgcn_mfma_f32_16x16x32_bf16(bc[ct], a2[kk], acc[ct], 0, 0, 0);
    if (kk == 3) {
      int cb = cwave + sub * 64;
      int t = row0 + lrow;
#pragma unroll
      for (int ct = 0; ct < 4; ++ct) {
        int col = cb + ct * 16 + lk * 4;
        __builtin_nontemporal_store(acc[ct], (f32x4*)(op + (size_t)t * QOUT + col));
        acc[ct] = (f32x4){0.f, 0.f, 0.f, 0.f};
      }
    }
#pragma unroll
    for (int ct = 0; ct < 4; ++ct) bc[ct] = bn[ct];
  }
}

extern "C" void kernel_launch(void* const* d_in, const int* in_sizes, int n_in,
                              void* d_out, int out_size, void* d_ws, size_t ws_size,
                              hipStream_t stream) {
  const float* h  = (const float*)d_in[0];
  const float* rw = (const float*)d_in[1];
  const float* qa = (const float*)d_in[2];
  const float* qb = (const float*)d_in[3];
  const float* va = (const float*)d_in[4];
  const float* vb = (const float*)d_in[5];
  float* out = (float*)d_out;
  char* ws = (char*)d_ws;

  short* Bq1 = (short*)(ws);                    // 512 KB each
  short* Bv1 = (short*)(ws + (512 << 10));
  short* Bq2 = (short*)(ws + (1024 << 10));
  short* Bv2 = (short*)(ws + (1536 << 10));

  k_pack<<<512, 256, 0, stream>>>(qa, qb, va, vb, Bq1, Bv1, Bq2, Bv2);
  k_fused<<<T_TOKENS / 16, 256, 0, stream>>>(h, rw, Bq1, Bv1, Bq2, Bv2, out);
}